// Round 1
// baseline (84.153 us; speedup 1.0000x reference)
//
#include <hip/hip_runtime.h>

// GPTQ int4 quantized linear: out[32,11008] = x[32,4096] @ W[4096,11008] + bias
// W[k,n] = scales[g,n] * (q[k,n] - (z[g,n]+1)),  g = k/128
// qweight: [K/8, N] int32, 8 k-nibbles per word (nibble j -> k = kk*8+j)
// qzeros:  [G, N/8] int32, 8 n-nibbles per word (nibble j -> n = nw*8+j)
//
// HARNESS DTYPES: fp16 tensors materialize as FLOAT32 (verified round 3).
// dur_us carries ~78us fixed harness work (268MB d_ws poison + restores, runs
// at the 6.3 TB/s achievable ceiling); controllable slice ~6us as of R7.
//
// Round-8: grid-balance pass.
//  - 344-block grid was lumpy (256+88 at <=2 blocks/CU co-residency: 88 CUs
//    carry 2 full blocks, 168 idle half the kernel -> makespan ~2x T_block).
//    Split each strip's K across 2 blocks: 688 half-cost blocks > 512
//    co-residency slots -> dynamic refill balances -> makespan ~1.45x T_half.
//    K-split (not N-split) keeps xp L2 traffic at 88 MB (N-split would double
//    it past the 4 MB/XCD L2).
//  - Cross-block combine via f32 atomicAdd (exactly 2 per address); out is
//    pre-initialized to bias by the pack kernel (stream order = init first).
//  - pack kernel regridded 64x256 -> 256x128 (all CUs engaged) + bias init.
// Dequant path (packed-f16 magic 0x000F000F|0x64006400, sigma permutation
// (0,4,1,5,2,6,3,7) applied to BOTH A and B) unchanged from R7.

#define M_ROWS 32
#define K_DIM  4096
#define N_DIM  11008
#define GS     128
#define BN     32
#define KSPLIT 8                          // waves per block = in-block K-slices
#define KHALF  2                          // K-split across blocks
#define BKR    (K_DIM / (KSPLIT * KHALF)) // 256 K per wave = 2 groups
#define NGRP   (BKR / GS)                 // 2
#define LDSW   33                         // +1 pad on 32-col rows

typedef _Float16 f16x2 __attribute__((ext_vector_type(2)));
typedef _Float16 f16x8 __attribute__((ext_vector_type(8)));
typedef unsigned int u32x4 __attribute__((ext_vector_type(4)));
typedef float  f32x4  __attribute__((ext_vector_type(4)));

// ---- kernel 1: pack x into f16 A-fragment order (sigma) + out := bias ----
// pack task gt in [0,16384): chunk c = b*2 + t, lane l:
//   element 2i   <- x[m][k0 + i]
//   element 2i+1 <- x[m][k0 + i + 4]   (m = 16t + (l&15), k0 = 32b + (l>>4)*8)
__global__ __launch_bounds__(128)
void pack_init_kernel(const float* __restrict__ x, const float* __restrict__ bias,
                      _Float16* __restrict__ xp, float* __restrict__ out) {
    const int gt = blockIdx.x * 128 + threadIdx.x;   // 0..32767
    if (gt < 16384) {
        const int c  = gt >> 6;
        const int l  = gt & 63;
        const int t  = c & 1;
        const int b  = c >> 1;
        const int m  = 16 * t + (l & 15);
        const int k0 = 32 * b + (l >> 4) * 8;
        const float4 f0 = *(const float4*)(&x[m * K_DIM + k0]);
        const float4 f1 = *(const float4*)(&x[m * K_DIM + k0 + 4]);
        f16x8 hv;
        hv[0] = (_Float16)f0.x; hv[1] = (_Float16)f1.x;
        hv[2] = (_Float16)f0.y; hv[3] = (_Float16)f1.y;
        hv[4] = (_Float16)f0.z; hv[5] = (_Float16)f1.z;
        hv[6] = (_Float16)f0.w; hv[7] = (_Float16)f1.w;
        *(f16x8*)(&xp[(size_t)gt * 8]) = hv;
    }
    // out[m][n] = bias[n] so kernel 2's split-K halves can atomicAdd partials.
    const float4* b4 = (const float4*)bias;
    float4*       o4 = (float4*)out;
    #pragma unroll
    for (int i = 0; i < 3; ++i) {
        const int idx = gt + i * 32768;              // 88064 float4 total
        if (idx < (M_ROWS * N_DIM / 4)) {
            o4[idx] = b4[idx % (N_DIM / 4)];
        }
    }
}

// dequant one qweight word -> 8-elem f16 B-fragment (k-order sigma)
__device__ inline f16x8 dequant_word(unsigned w, f16x2 scv, f16x2 zv) {
    const f16x2 k1024 = {(_Float16)1024, (_Float16)1024};
    u32x4 u;
    #pragma unroll
    for (int i = 0; i < 4; ++i) {
        const unsigned t = ((w >> (4 * i)) & 0x000F000Fu) | 0x64006400u;
        f16x2 p = __builtin_bit_cast(f16x2, t);
        p = p - k1024;                                  // exact: (q_i, q_{i+4})
        p = __builtin_elementwise_fma(p, scv, zv);      // v_pk_fma_f16
        u[i] = __builtin_bit_cast(unsigned, p);
    }
    return __builtin_bit_cast(f16x8, u);
}

// ---- kernel 2: fused MFMA + in-block LDS combine + cross-block atomic ----
__global__ __launch_bounds__(512, 4)
void gptq_fused_kernel(const _Float16* __restrict__ xp,
                       const int* __restrict__ qweight,
                       const int* __restrict__ qzeros,
                       const float* __restrict__ scales,
                       float* __restrict__ out)
{
    __shared__ float lds[KSPLIT * M_ROWS * LDSW];   // 33.8 KB

    const int tid  = threadIdx.x;
    const int lane = tid & 63;
    const int kb   = tid >> 6;               // wave index = in-block K-slice
    const int kh   = blockIdx.x & 1;         // K-half of this block
    const int n0   = (blockIdx.x >> 1) * BN; // 32-col strip
    const int slice = kh * KSPLIT + kb;      // global 256-k slice, 0..15

    const int col  = lane & 15;
    const int quad = lane >> 4;
    const int nA   = n0 + col;               // n-subtile 0
    const int nB   = n0 + 16 + col;          // n-subtile 1

    f32x4 accA0 = {0.f,0.f,0.f,0.f}, accA1 = {0.f,0.f,0.f,0.f};
    f32x4 accB0 = {0.f,0.f,0.f,0.f}, accB1 = {0.f,0.f,0.f,0.f};

    #pragma unroll
    for (int gl = 0; gl < NGRP; ++gl) {
        const int g   = slice * NGRP + gl;   // global group 0..31
        const int zwA = qzeros[g * (N_DIM / 8) + (nA >> 3)];
        const int zwB = qzeros[g * (N_DIM / 8) + (nB >> 3)];
        const float scA = scales[g * N_DIM + nA];
        const float scB = scales[g * N_DIM + nB];
        const float zsA = -((float)(((zwA >> ((nA & 7) * 4)) & 0xF) + 1)) * scA;
        const float zsB = -((float)(((zwB >> ((nB & 7) * 4)) & 0xF) + 1)) * scB;
        const f16x2 scvA = {(_Float16)scA, (_Float16)scA};
        const f16x2 scvB = {(_Float16)scB, (_Float16)scB};
        const f16x2 zvA  = {(_Float16)zsA, (_Float16)zsA};
        const f16x2 zvB  = {(_Float16)zsB, (_Float16)zsB};

        #pragma unroll
        for (int ks = 0; ks < 4; ++ks) {
            const int wrow = slice * (BKR / 8) + gl * (GS / 8) + ks * 4 + quad;
            const unsigned wA = (unsigned)qweight[wrow * N_DIM + nA];
            const unsigned wB = (unsigned)qweight[wrow * N_DIM + nB];
            const f16x8 bfA = dequant_word(wA, scvA, zvA);
            const f16x8 bfB = dequant_word(wB, scvB, zvB);
            const int b = slice * 8 + gl * 4 + ks;   // 32-k block index, 0..127
            const f16x8 a0 = *(const f16x8*)(&xp[((b * 2 + 0) * 64 + lane) * 8]);
            const f16x8 a1 = *(const f16x8*)(&xp[((b * 2 + 1) * 64 + lane) * 8]);
            accA0 = __builtin_amdgcn_mfma_f32_16x16x32_f16(a0, bfA, accA0, 0, 0, 0);
            accA1 = __builtin_amdgcn_mfma_f32_16x16x32_f16(a1, bfA, accA1, 0, 0, 0);
            accB0 = __builtin_amdgcn_mfma_f32_16x16x32_f16(a0, bfB, accB0, 0, 0, 0);
            accB1 = __builtin_amdgcn_mfma_f32_16x16x32_f16(a1, bfB, accB1, 0, 0, 0);
        }
    }

    // ---- stash per-wave partials: lds[kb][m][c], C/D layout row=quad*4+r ----
    float* slab = &lds[kb * M_ROWS * LDSW];
    #pragma unroll
    for (int r = 0; r < 4; ++r) {
        const int m = quad * 4 + r;
        slab[m * LDSW + col]             = accA0[r];
        slab[(16 + m) * LDSW + col]      = accA1[r];
        slab[m * LDSW + 16 + col]        = accB0[r];
        slab[(16 + m) * LDSW + 16 + col] = accB1[r];
    }
    __syncthreads();

    // ---- 8-way combine + cross-block atomic: 1024 outs, 2 per thread ----
    #pragma unroll
    for (int i = 0; i < 2; ++i) {
        const int idx = i * 512 + tid;    // 0..1023
        const int m   = idx >> 5;
        const int cc  = idx & 31;
        float sum = 0.f;
        #pragma unroll
        for (int w = 0; w < KSPLIT; ++w)
            sum += lds[w * M_ROWS * LDSW + m * LDSW + cc];
        atomicAdd(&out[m * N_DIM + n0 + cc], sum);   // out pre-set to bias
    }
}

extern "C" void kernel_launch(void* const* d_in, const int* in_sizes, int n_in,
                              void* d_out, int out_size, void* d_ws, size_t ws_size,
                              hipStream_t stream) {
    const float* x       = (const float*)d_in[0];
    const int*   qweight = (const int*)d_in[1];
    const int*   qzeros  = (const int*)d_in[2];
    const float* scales  = (const float*)d_in[3];
    const float* bias    = (const float*)d_in[4];
    float*       out     = (float*)d_out;

    _Float16* xp = (_Float16*)d_ws;   // 256 KB packed x

    pack_init_kernel<<<256, 128, 0, stream>>>(x, bias, xp, out);
    gptq_fused_kernel<<<(N_DIM / BN) * KHALF, 512, 0, stream>>>(xp, qweight, qzeros,
                                                                scales, out);
}